// Round 1
// baseline (275.155 us; speedup 1.0000x reference)
//
#include <hip/hip_runtime.h>
#include <hip/hip_bf16.h>
#include <stdint.h>

#define B_   256
#define S_   32
#define L_   20
#define D_   512
#define IN_  1024
#define M_ROWS 8448   // 256 self rows + 8192 social rows
#define NT   512      // embd dim

#define BM 128
#define BN 128
#define BK 64

typedef __attribute__((ext_vector_type(4))) float f32x4;
typedef __attribute__((ext_vector_type(8))) short s16x8;

static __device__ __forceinline__ float wave_reduce_sum(float v) {
#pragma unroll
  for (int off = 32; off > 0; off >>= 1) v += __shfl_xor(v, off);
  return v;
}

// ---------------------------------------------------------------------------
// Kernel A: masked mean over L, concat(users, items), output bf16 [8448][1024]
// row r: r < 256 -> self user b=r ; r >= 256 -> social idx = r-256 (b*32+s)
// ---------------------------------------------------------------------------
__global__ __launch_bounds__(256) void agg_kernel(
    const float* __restrict__ self_users, const float* __restrict__ self_items,
    const float* __restrict__ self_mask,
    const float* __restrict__ soc_users, const float* __restrict__ soc_items,
    const float* __restrict__ soc_mask,
    __hip_bfloat16* __restrict__ agg) {
  int r = blockIdx.x;
  const float *uptr, *iptr, *mptr;
  if (r < B_) {
    uptr = self_users + (size_t)r * (L_ * D_);
    iptr = self_items + (size_t)r * (L_ * D_);
    mptr = self_mask + (size_t)r * L_;
  } else {
    int idx = r - B_;
    uptr = soc_users + (size_t)idx * (L_ * D_);
    iptr = soc_items + (size_t)idx * (L_ * D_);
    mptr = soc_mask + (size_t)idx * L_;
  }
  __shared__ float mk[L_];
  int tid = threadIdx.x;
  if (tid < L_) mk[tid] = mptr[tid];
  __syncthreads();
  float msum = 1e-4f;
#pragma unroll
  for (int l = 0; l < L_; ++l) msum += mk[l];
  float inv = 1.0f / msum;

  const float* base = (tid < 128) ? uptr : iptr;
  int c = (tid & 127) * 4;
  f32x4 acc = {0.f, 0.f, 0.f, 0.f};
#pragma unroll
  for (int l = 0; l < L_; ++l) {
    f32x4 v = *(const f32x4*)(base + (size_t)l * D_ + c);
    acc += v * mk[l];
  }
  acc *= inv;
  size_t o = (size_t)r * IN_ + ((tid < 128) ? 0 : D_) + c;
  __hip_bfloat16* ap = agg + o;
  ap[0] = __float2bfloat16(acc[0]);
  ap[1] = __float2bfloat16(acc[1]);
  ap[2] = __float2bfloat16(acc[2]);
  ap[3] = __float2bfloat16(acc[3]);
}

// ---------------------------------------------------------------------------
// Kernel: convert ml_user_w [512][1024] f32 -> bf16
// ---------------------------------------------------------------------------
__global__ __launch_bounds__(256) void cvt_w_kernel(
    const float* __restrict__ w, __hip_bfloat16* __restrict__ wb) {
  int i = (blockIdx.x * 256 + threadIdx.x) * 4;
  f32x4 v = *(const f32x4*)(w + i);
  wb[i + 0] = __float2bfloat16(v[0]);
  wb[i + 1] = __float2bfloat16(v[1]);
  wb[i + 2] = __float2bfloat16(v[2]);
  wb[i + 3] = __float2bfloat16(v[3]);
}

// ---------------------------------------------------------------------------
// Kernel B: embd[M][512] = relu(agg[M][1024] @ W^T + bias), bf16 MFMA, f32 out
// W stored [512][1024] row-major = B^T layout (K contiguous) — ideal for MFMA.
// 128x128 tile, BK=64, 4 waves, 16x16x32 MFMA, global_load_lds width 16.
// ---------------------------------------------------------------------------
__global__ __launch_bounds__(256) void gemm_bias_relu_kernel(
    const __hip_bfloat16* __restrict__ A,   // [M_ROWS][IN_]
    const __hip_bfloat16* __restrict__ Bw,  // [NT][IN_]
    const float* __restrict__ bias,         // [NT]
    float* __restrict__ C) {                // [M_ROWS][NT]
  __shared__ ushort Al[BM * BK];
  __shared__ ushort Bl[BN * BK];
  int tid = threadIdx.x;
  int lane = tid & 63;
  int wid = tid >> 6;
  int wr = wid >> 1, wc = wid & 1;
  int tn = blockIdx.x & 3;         // NT/BN = 4
  int tm = blockIdx.x >> 2;        // 0..65
  const int K = IN_;

  // staging: thread t loads 16B: row = t>>3 (+32 per issue), elem col = (t&7)*8
  int srow = tid >> 3;
  int scol = (tid & 7) * 8;
  const ushort* ga = (const ushort*)A + (size_t)(tm * BM + srow) * K + scol;
  const ushort* gb = (const ushort*)Bw + (size_t)(tn * BN + srow) * K + scol;
  ushort* la = Al + tid * 8;   // linear: (t>>3)*BK + (t&7)*8 == t*8
  ushort* lb = Bl + tid * 8;

  f32x4 acc[4][4];
#pragma unroll
  for (int i = 0; i < 4; ++i)
#pragma unroll
    for (int j = 0; j < 4; ++j) acc[i][j] = {0.f, 0.f, 0.f, 0.f};

  for (int kt = 0; kt < K; kt += BK) {
    __syncthreads();
#pragma unroll
    for (int it = 0; it < 4; ++it) {
      __builtin_amdgcn_global_load_lds(
          (const __attribute__((address_space(1))) void*)(ga + (size_t)(it * 32) * K + kt),
          (__attribute__((address_space(3))) void*)(la + it * 32 * BK), 16, 0, 0);
      __builtin_amdgcn_global_load_lds(
          (const __attribute__((address_space(1))) void*)(gb + (size_t)(it * 32) * K + kt),
          (__attribute__((address_space(3))) void*)(lb + it * 32 * BK), 16, 0, 0);
    }
    __syncthreads();  // drains vmcnt before barrier -> LDS ready
#pragma unroll
    for (int kk = 0; kk < BK; kk += 32) {
      s16x8 af[4], bf[4];
#pragma unroll
      for (int i = 0; i < 4; ++i)
        af[i] = *(const s16x8*)(Al + (wr * 64 + i * 16 + (lane & 15)) * BK + kk + (lane >> 4) * 8);
#pragma unroll
      for (int j = 0; j < 4; ++j)
        bf[j] = *(const s16x8*)(Bl + (wc * 64 + j * 16 + (lane & 15)) * BK + kk + (lane >> 4) * 8);
#pragma unroll
      for (int i = 0; i < 4; ++i)
#pragma unroll
        for (int j = 0; j < 4; ++j)
          acc[i][j] = __builtin_amdgcn_mfma_f32_16x16x32_bf16(af[i], bf[j], acc[i][j], 0, 0, 0);
    }
  }

  // epilogue: C/D layout col=lane&15, row=(lane>>4)*4+reg (m89-verified)
  int row0 = tm * BM + wr * 64 + (lane >> 4) * 4;
  int col0 = tn * BN + wc * 64 + (lane & 15);
#pragma unroll
  for (int j = 0; j < 4; ++j) {
    int col = col0 + j * 16;
    float bv = bias[col];
#pragma unroll
    for (int i = 0; i < 4; ++i) {
      int row = row0 + i * 16;
#pragma unroll
      for (int q = 0; q < 4; ++q) {
        float v = acc[i][j][q] + bv;
        C[(size_t)(row + q) * NT + col] = v > 0.f ? v : 0.f;
      }
    }
  }
}

// ---------------------------------------------------------------------------
// Kernel C: per-user softmax attention over 32 social neighbors (f32)
// social_attn[b][d] = sum_s softmax_s(self_embd[b].social_embd[b,s]) * social_embd[b,s,d]
// ---------------------------------------------------------------------------
__global__ __launch_bounds__(256) void attn_kernel(
    const float* __restrict__ embd, float* __restrict__ social_attn) {
  int b = blockIdx.x;
  int tid = threadIdx.x, lane = tid & 63, wid = tid >> 6;
  __shared__ float selfe[D_];
  __shared__ float sc[S_];
  __shared__ float att[S_];
  if (tid < 128) *(f32x4*)&selfe[tid * 4] = *(const f32x4*)&embd[(size_t)b * NT + tid * 4];
  __syncthreads();
  f32x4 s0 = *(const f32x4*)&selfe[lane * 8];
  f32x4 s1 = *(const f32x4*)&selfe[lane * 8 + 4];
  const float* socbase = embd + (size_t)(B_ + b * S_) * NT;
#pragma unroll
  for (int q = 0; q < 8; ++q) {
    int s = wid * 8 + q;
    const float* rp = socbase + (size_t)s * NT + lane * 8;
    f32x4 v0 = *(const f32x4*)rp;
    f32x4 v1 = *(const f32x4*)(rp + 4);
    float p = s0[0]*v0[0] + s0[1]*v0[1] + s0[2]*v0[2] + s0[3]*v0[3]
            + s1[0]*v1[0] + s1[1]*v1[1] + s1[2]*v1[2] + s1[3]*v1[3];
    p = wave_reduce_sum(p);
    if (lane == 0) sc[s] = p;
  }
  __syncthreads();
  if (wid == 0) {
    float v = (lane < S_) ? sc[lane] : -3.4e38f;
    float m = v;
#pragma unroll
    for (int off = 16; off > 0; off >>= 1) m = fmaxf(m, __shfl_xor(m, off));
    float e = (lane < S_) ? expf(v - m) : 0.f;
    float sum = e;
#pragma unroll
    for (int off = 16; off > 0; off >>= 1) sum += __shfl_xor(sum, off);
    if (lane < S_) att[lane] = e / sum;
  }
  __syncthreads();
  float a0 = 0.f, a1 = 0.f;
#pragma unroll 4
  for (int s = 0; s < S_; ++s) {
    float w = att[s];
    a0 += w * socbase[(size_t)s * NT + tid];
    a1 += w * socbase[(size_t)s * NT + tid + 256];
  }
  social_attn[(size_t)b * NT + tid] = a0;
  social_attn[(size_t)b * NT + tid + 256] = a1;
}

// ---------------------------------------------------------------------------
// Kernel D1: rate scores. score[v][b] = w2 . relu(W1 @ e_vb + b1)
// v=0: e = self_embd[b] (embd rows 0..255); v=1: e = social_attn[b]
// wave-per-row of W1 (coalesced 2KB/row), shuffle reduce.
// ---------------------------------------------------------------------------
__global__ __launch_bounds__(256) void rate_score_kernel(
    const float* __restrict__ embd, const float* __restrict__ social_attn,
    const float* __restrict__ W1, const float* __restrict__ b1,
    const float* __restrict__ w2, float* __restrict__ scores) {
  int v = blockIdx.x >> 8;
  int b = blockIdx.x & 255;
  const float* e = v ? (social_attn + (size_t)b * NT) : (embd + (size_t)b * NT);
  __shared__ float el[D_];
  __shared__ float wpart[4];
  int tid = threadIdx.x, lane = tid & 63, wid = tid >> 6;
  if (tid < 128) *(f32x4*)&el[tid * 4] = *(const f32x4*)&e[tid * 4];
  __syncthreads();
  f32x4 e0 = *(const f32x4*)&el[lane * 8];
  f32x4 e1 = *(const f32x4*)&el[lane * 8 + 4];
  float part = 0.f;
  for (int r = wid; r < D_; r += 4) {
    const float* wr = W1 + (size_t)r * D_ + lane * 8;
    f32x4 w0 = *(const f32x4*)wr;
    f32x4 w1v = *(const f32x4*)(wr + 4);
    float p = e0[0]*w0[0] + e0[1]*w0[1] + e0[2]*w0[2] + e0[3]*w0[3]
            + e1[0]*w1v[0] + e1[1]*w1v[1] + e1[2]*w1v[2] + e1[3]*w1v[3];
    p = wave_reduce_sum(p);
    float t = p + b1[r];
    t = t > 0.f ? t : 0.f;
    part += w2[r] * t;   // identical across all lanes of the wave
  }
  if (lane == 0) wpart[wid] = part;
  __syncthreads();
  if (tid == 0) scores[v * B_ + b] = wpart[0] + wpart[1] + wpart[2] + wpart[3];
}

// ---------------------------------------------------------------------------
// Kernel D2: batch softmax over 256 scores + weighted pool -> out[v][512]
// ---------------------------------------------------------------------------
__global__ __launch_bounds__(256) void pool_kernel(
    const float* __restrict__ embd, const float* __restrict__ social_attn,
    const float* __restrict__ scores, float* __restrict__ out) {
  int v = blockIdx.x;
  const float* E = v ? social_attn : embd;  // embd rows 0..255 = self_embd
  const float* sc = scores + v * B_;
  __shared__ float att[B_];
  __shared__ float red[8];
  int tid = threadIdx.x, lane = tid & 63, wid = tid >> 6;
  float s = sc[tid];
  float m = s;
#pragma unroll
  for (int off = 32; off > 0; off >>= 1) m = fmaxf(m, __shfl_xor(m, off));
  if (lane == 0) red[wid] = m;
  __syncthreads();
  m = fmaxf(fmaxf(red[0], red[1]), fmaxf(red[2], red[3]));
  float ev = expf(s - m);
  float sum = wave_reduce_sum(ev);
  if (lane == 0) red[4 + wid] = sum;
  __syncthreads();
  sum = red[4] + red[5] + red[6] + red[7];
  att[tid] = ev / sum;
  __syncthreads();
  float a0 = 0.f, a1 = 0.f;
#pragma unroll 4
  for (int b = 0; b < B_; ++b) {
    float w = att[b];
    a0 += w * E[(size_t)b * NT + tid];
    a1 += w * E[(size_t)b * NT + tid + 256];
  }
  out[v * NT + tid] = a0;
  out[v * NT + tid + 256] = a1;
}

// ---------------------------------------------------------------------------
extern "C" void kernel_launch(void* const* d_in, const int* in_sizes, int n_in,
                              void* d_out, int out_size, void* d_ws, size_t ws_size,
                              hipStream_t stream) {
  const float* self_users = (const float*)d_in[0];
  const float* self_items = (const float*)d_in[1];
  const float* self_mask  = (const float*)d_in[2];
  const float* soc_users  = (const float*)d_in[3];
  const float* soc_items  = (const float*)d_in[4];
  const float* soc_mask   = (const float*)d_in[5];
  const float* ml_user_w  = (const float*)d_in[6];
  const float* ml_user_b  = (const float*)d_in[7];
  const float* ml_w1      = (const float*)d_in[8];
  const float* ml_b1      = (const float*)d_in[9];
  const float* ml_w2      = (const float*)d_in[10];

  char* ws = (char*)d_ws;
  __hip_bfloat16* agg = (__hip_bfloat16*)ws;               // 8448*1024*2 = 17,301,504 B
  __hip_bfloat16* wb  = (__hip_bfloat16*)(ws + 17301504);  // 512*1024*2  =  1,048,576 B
  float* embd         = (float*)(ws + 18350080);           // 8448*512*4  = 17,301,504 B
  float* social_attn  = (float*)(ws + 35651584);           // 256*512*4   =    524,288 B
  float* scores       = (float*)(ws + 36175872);           // 512*4       =      2,048 B

  hipLaunchKernelGGL(agg_kernel, dim3(M_ROWS), dim3(256), 0, stream,
                     self_users, self_items, self_mask, soc_users, soc_items,
                     soc_mask, agg);
  hipLaunchKernelGGL(cvt_w_kernel, dim3(512), dim3(256), 0, stream, ml_user_w, wb);
  hipLaunchKernelGGL(gemm_bias_relu_kernel, dim3((M_ROWS / BM) * (NT / BN)),
                     dim3(256), 0, stream, agg, wb, ml_user_b, embd);
  hipLaunchKernelGGL(attn_kernel, dim3(B_), dim3(256), 0, stream, embd, social_attn);
  hipLaunchKernelGGL(rate_score_kernel, dim3(512), dim3(256), 0, stream,
                     embd, social_attn, ml_w1, ml_b1, ml_w2, scores);
  hipLaunchKernelGGL(pool_kernel, dim3(2), dim3(256), 0, stream,
                     embd, social_attn, scores, (float*)d_out);
}

// Round 2
// 256.965 us; speedup vs baseline: 1.0708x; 1.0708x over previous
//
#include <hip/hip_runtime.h>
#include <hip/hip_bf16.h>
#include <stdint.h>

#define B_   256
#define S_   32
#define L_   20
#define D_   512
#define IN_  1024
#define M_ROWS 8448   // 256 self rows + 8192 social rows
#define NT   512      // embd dim

// GEMM tile: 64x128, BK=64 -> 132*4 = 528 blocks (~2 blocks/CU)
#define GBM 64
#define GBN 128
#define GBK 64

typedef __attribute__((ext_vector_type(4))) float f32x4;
typedef __attribute__((ext_vector_type(8))) short s16x8;

static __device__ __forceinline__ float wave_reduce_sum(float v) {
#pragma unroll
  for (int off = 32; off > 0; off >>= 1) v += __shfl_xor(v, off);
  return v;
}

// ---------------------------------------------------------------------------
// Kernel A: masked mean over L, concat(users, items), output bf16 [8448][1024]
// row r: r < 256 -> self user b=r ; r >= 256 -> social idx = r-256 (b*32+s)
// ---------------------------------------------------------------------------
__global__ __launch_bounds__(256) void agg_kernel(
    const float* __restrict__ self_users, const float* __restrict__ self_items,
    const float* __restrict__ self_mask,
    const float* __restrict__ soc_users, const float* __restrict__ soc_items,
    const float* __restrict__ soc_mask,
    __hip_bfloat16* __restrict__ agg) {
  int r = blockIdx.x;
  const float *uptr, *iptr, *mptr;
  if (r < B_) {
    uptr = self_users + (size_t)r * (L_ * D_);
    iptr = self_items + (size_t)r * (L_ * D_);
    mptr = self_mask + (size_t)r * L_;
  } else {
    int idx = r - B_;
    uptr = soc_users + (size_t)idx * (L_ * D_);
    iptr = soc_items + (size_t)idx * (L_ * D_);
    mptr = soc_mask + (size_t)idx * L_;
  }
  __shared__ float mk[L_];
  int tid = threadIdx.x;
  if (tid < L_) mk[tid] = mptr[tid];
  __syncthreads();
  float msum = 1e-4f;
#pragma unroll
  for (int l = 0; l < L_; ++l) msum += mk[l];
  float inv = 1.0f / msum;

  const float* base = (tid < 128) ? uptr : iptr;
  int c = (tid & 127) * 4;
  f32x4 acc = {0.f, 0.f, 0.f, 0.f};
#pragma unroll
  for (int l = 0; l < L_; ++l) {
    f32x4 v = *(const f32x4*)(base + (size_t)l * D_ + c);
    acc += v * mk[l];
  }
  acc *= inv;
  size_t o = (size_t)r * IN_ + ((tid < 128) ? 0 : D_) + c;
  __hip_bfloat16* ap = agg + o;
  ap[0] = __float2bfloat16(acc[0]);
  ap[1] = __float2bfloat16(acc[1]);
  ap[2] = __float2bfloat16(acc[2]);
  ap[3] = __float2bfloat16(acc[3]);
}

// ---------------------------------------------------------------------------
// convert ml_user_w [512][1024] f32 -> bf16
// ---------------------------------------------------------------------------
__global__ __launch_bounds__(256) void cvt_w_kernel(
    const float* __restrict__ w, __hip_bfloat16* __restrict__ wb) {
  int i = (blockIdx.x * 256 + threadIdx.x) * 4;
  f32x4 v = *(const f32x4*)(w + i);
  wb[i + 0] = __float2bfloat16(v[0]);
  wb[i + 1] = __float2bfloat16(v[1]);
  wb[i + 2] = __float2bfloat16(v[2]);
  wb[i + 3] = __float2bfloat16(v[3]);
}

// ---------------------------------------------------------------------------
// Kernel B: embd[M][512] = relu(agg[M][1024] @ W^T + bias), bf16 MFMA, f32 out
// 64x128 tile, BK=64, 4 waves (2x2, wave tile 32x64), 16x16x32 MFMA,
// global_load_lds width 16, XCD-chunk-swizzled blockIdx (528 = 8*66).
// ---------------------------------------------------------------------------
__global__ __launch_bounds__(256) void gemm_bias_relu_kernel(
    const __hip_bfloat16* __restrict__ A,   // [M_ROWS][IN_]
    const __hip_bfloat16* __restrict__ Bw,  // [NT][IN_]
    const float* __restrict__ bias,         // [NT]
    float* __restrict__ C) {                // [M_ROWS][NT]
  __shared__ ushort Al[GBM * GBK];  // 8 KB
  __shared__ ushort Bl[GBN * GBK];  // 16 KB
  int tid = threadIdx.x;
  int lane = tid & 63;
  int wid = tid >> 6;
  int wr = wid >> 1, wc = wid & 1;
  // bijective XCD chunk swizzle: 528 blocks = 8 XCDs * 66
  int logical = (blockIdx.x & 7) * 66 + (blockIdx.x >> 3);
  int tn = logical & 3;         // 4 n-tiles of 128
  int tm = logical >> 2;        // 132 m-tiles of 64
  const int K = IN_;

  int srow = tid >> 3;          // 0..31
  int scol = (tid & 7) * 8;
  const ushort* ga = (const ushort*)A + (size_t)(tm * GBM + srow) * K + scol;
  const ushort* gb = (const ushort*)Bw + (size_t)(tn * GBN + srow) * K + scol;
  ushort* la = Al + tid * 8;    // linear: (t>>3)*GBK + (t&7)*8 == t*8
  ushort* lb = Bl + tid * 8;

  f32x4 acc[2][4];
#pragma unroll
  for (int i = 0; i < 2; ++i)
#pragma unroll
    for (int j = 0; j < 4; ++j) acc[i][j] = {0.f, 0.f, 0.f, 0.f};

  for (int kt = 0; kt < K; kt += GBK) {
    __syncthreads();
#pragma unroll
    for (int it = 0; it < 2; ++it)
      __builtin_amdgcn_global_load_lds(
          (const __attribute__((address_space(1))) void*)(ga + (size_t)(it * 32) * K + kt),
          (__attribute__((address_space(3))) void*)(la + it * 32 * GBK), 16, 0, 0);
#pragma unroll
    for (int it = 0; it < 4; ++it)
      __builtin_amdgcn_global_load_lds(
          (const __attribute__((address_space(1))) void*)(gb + (size_t)(it * 32) * K + kt),
          (__attribute__((address_space(3))) void*)(lb + it * 32 * GBK), 16, 0, 0);
    __syncthreads();
#pragma unroll
    for (int kk = 0; kk < GBK; kk += 32) {
      s16x8 af[2], bf[4];
#pragma unroll
      for (int i = 0; i < 2; ++i)
        af[i] = *(const s16x8*)(Al + (wr * 32 + i * 16 + (lane & 15)) * GBK + kk + (lane >> 4) * 8);
#pragma unroll
      for (int j = 0; j < 4; ++j)
        bf[j] = *(const s16x8*)(Bl + (wc * 64 + j * 16 + (lane & 15)) * GBK + kk + (lane >> 4) * 8);
#pragma unroll
      for (int i = 0; i < 2; ++i)
#pragma unroll
        for (int j = 0; j < 4; ++j)
          acc[i][j] = __builtin_amdgcn_mfma_f32_16x16x32_bf16(af[i], bf[j], acc[i][j], 0, 0, 0);
    }
  }

  // C/D layout: col=lane&15, row=(lane>>4)*4+reg (m89-verified)
  int row0 = tm * GBM + wr * 32 + (lane >> 4) * 4;
  int col0 = tn * GBN + wc * 64 + (lane & 15);
#pragma unroll
  for (int j = 0; j < 4; ++j) {
    int col = col0 + j * 16;
    float bv = bias[col];
#pragma unroll
    for (int i = 0; i < 2; ++i) {
      int row = row0 + i * 16;
#pragma unroll
      for (int q = 0; q < 4; ++q) {
        float v = acc[i][j][q] + bv;
        C[(size_t)(row + q) * NT + col] = v > 0.f ? v : 0.f;
      }
    }
  }
}

// ---------------------------------------------------------------------------
// Kernel C: per-user softmax attention over 32 social neighbors (f32).
// Social rows staged in LDS once (64 KB) -> single global pass.
// ---------------------------------------------------------------------------
__global__ __launch_bounds__(256) void attn_kernel(
    const float* __restrict__ embd, float* __restrict__ social_attn) {
  int b = blockIdx.x;
  int tid = threadIdx.x, lane = tid & 63, wid = tid >> 6;
  __shared__ float soc[S_ * D_];  // 64 KB
  __shared__ float sc[S_];
  __shared__ float att[S_];
  const float* socbase = embd + (size_t)(B_ + b * S_) * NT;
#pragma unroll
  for (int it = 0; it < 16; ++it) {
    int idx = it * 1024 + tid * 4;
    *(f32x4*)&soc[idx] = *(const f32x4*)&socbase[idx];
  }
  // self row into regs (redundant per wave, from L1/L2)
  const float* se = embd + (size_t)b * NT + lane * 8;
  f32x4 s0 = *(const f32x4*)se;
  f32x4 s1 = *(const f32x4*)(se + 4);
  __syncthreads();
#pragma unroll
  for (int q = 0; q < 8; ++q) {
    int s = wid * 8 + q;
    const float* rp = soc + s * D_ + lane * 8;
    f32x4 v0 = *(const f32x4*)rp;
    f32x4 v1 = *(const f32x4*)(rp + 4);
    float p = s0[0]*v0[0] + s0[1]*v0[1] + s0[2]*v0[2] + s0[3]*v0[3]
            + s1[0]*v1[0] + s1[1]*v1[1] + s1[2]*v1[2] + s1[3]*v1[3];
    p = wave_reduce_sum(p);
    if (lane == 0) sc[s] = p;
  }
  __syncthreads();
  if (wid == 0) {
    float v = (lane < S_) ? sc[lane] : -3.4e38f;
    float m = v;
#pragma unroll
    for (int off = 16; off > 0; off >>= 1) m = fmaxf(m, __shfl_xor(m, off));
    float e = (lane < S_) ? expf(v - m) : 0.f;
    float sum = e;
#pragma unroll
    for (int off = 16; off > 0; off >>= 1) sum += __shfl_xor(sum, off);
    if (lane < S_) att[lane] = e / sum;
  }
  __syncthreads();
  float a0 = 0.f, a1 = 0.f;
#pragma unroll 8
  for (int s = 0; s < S_; ++s) {
    float w = att[s];
    a0 += w * soc[s * D_ + tid];
    a1 += w * soc[s * D_ + tid + 256];
  }
  social_attn[(size_t)b * NT + tid] = a0;
  social_attn[(size_t)b * NT + tid + 256] = a1;
}

// ---------------------------------------------------------------------------
// Kernel D1: rate scores, both variants per block (W1 row read once for both).
// score[0][b] = w2 . relu(W1 @ self_embd[b] + b1); score[1][b] same on attn.
// ---------------------------------------------------------------------------
__global__ __launch_bounds__(256) void rate_score_kernel(
    const float* __restrict__ embd, const float* __restrict__ social_attn,
    const float* __restrict__ W1, const float* __restrict__ b1,
    const float* __restrict__ w2, float* __restrict__ scores) {
  int b = blockIdx.x;
  __shared__ float eS[D_], eA[D_];
  __shared__ float wpS[4], wpA[4];
  int tid = threadIdx.x, lane = tid & 63, wid = tid >> 6;
  if (tid < 128) {
    *(f32x4*)&eS[tid * 4] = *(const f32x4*)&embd[(size_t)b * NT + tid * 4];
  } else {
    int t = tid - 128;
    *(f32x4*)&eA[t * 4] = *(const f32x4*)&social_attn[(size_t)b * NT + t * 4];
  }
  __syncthreads();
  f32x4 es0 = *(const f32x4*)&eS[lane * 8];
  f32x4 es1 = *(const f32x4*)&eS[lane * 8 + 4];
  f32x4 ea0 = *(const f32x4*)&eA[lane * 8];
  f32x4 ea1 = *(const f32x4*)&eA[lane * 8 + 4];
  float partS = 0.f, partA = 0.f;
  for (int r = wid; r < D_; r += 4) {
    const float* wr_ = W1 + (size_t)r * D_ + lane * 8;
    f32x4 w0 = *(const f32x4*)wr_;
    f32x4 w1v = *(const f32x4*)(wr_ + 4);
    float pS = es0[0]*w0[0] + es0[1]*w0[1] + es0[2]*w0[2] + es0[3]*w0[3]
             + es1[0]*w1v[0] + es1[1]*w1v[1] + es1[2]*w1v[2] + es1[3]*w1v[3];
    float pA = ea0[0]*w0[0] + ea0[1]*w0[1] + ea0[2]*w0[2] + ea0[3]*w0[3]
             + ea1[0]*w1v[0] + ea1[1]*w1v[1] + ea1[2]*w1v[2] + ea1[3]*w1v[3];
#pragma unroll
    for (int off = 32; off > 0; off >>= 1) {
      pS += __shfl_xor(pS, off);
      pA += __shfl_xor(pA, off);
    }
    float bv = b1[r], wv = w2[r];
    float tS = pS + bv; tS = tS > 0.f ? tS : 0.f;
    float tA = pA + bv; tA = tA > 0.f ? tA : 0.f;
    partS += wv * tS;
    partA += wv * tA;
  }
  if (lane == 0) { wpS[wid] = partS; wpA[wid] = partA; }
  __syncthreads();
  if (tid == 0) scores[b] = wpS[0] + wpS[1] + wpS[2] + wpS[3];
  if (tid == 1) scores[B_ + b] = wpA[0] + wpA[1] + wpA[2] + wpA[3];
}

// ---------------------------------------------------------------------------
// Kernel D2a: batch softmax (recomputed per block) + partial pool over 32 b's.
// grid 16: v = blk>>3, chunk = blk&7. partial[blk][512] in ws.
// ---------------------------------------------------------------------------
__global__ __launch_bounds__(256) void pool_partial_kernel(
    const float* __restrict__ embd, const float* __restrict__ social_attn,
    const float* __restrict__ scores, float* __restrict__ partial) {
  int v = blockIdx.x >> 3;
  int chunk = blockIdx.x & 7;
  const float* E = v ? social_attn : embd;  // embd rows 0..255 = self_embd
  const float* sc = scores + v * B_;
  __shared__ float att[B_];
  __shared__ float red[8];
  int tid = threadIdx.x, lane = tid & 63, wid = tid >> 6;
  float s = sc[tid];
  float m = s;
#pragma unroll
  for (int off = 32; off > 0; off >>= 1) m = fmaxf(m, __shfl_xor(m, off));
  if (lane == 0) red[wid] = m;
  __syncthreads();
  m = fmaxf(fmaxf(red[0], red[1]), fmaxf(red[2], red[3]));
  float ev = expf(s - m);
  float sum = wave_reduce_sum(ev);
  if (lane == 0) red[4 + wid] = sum;
  __syncthreads();
  sum = red[4] + red[5] + red[6] + red[7];
  att[tid] = ev / sum;
  __syncthreads();
  float a0 = 0.f, a1 = 0.f;
#pragma unroll 8
  for (int q = 0; q < 32; ++q) {
    int b = chunk * 32 + q;
    float w = att[b];
    a0 += w * E[(size_t)b * NT + tid];
    a1 += w * E[(size_t)b * NT + tid + 256];
  }
  partial[(size_t)blockIdx.x * NT + tid] = a0;
  partial[(size_t)blockIdx.x * NT + tid + 256] = a1;
}

// ---------------------------------------------------------------------------
// Kernel D2b: final reduce of 8 partials per v -> out[v][512]
// ---------------------------------------------------------------------------
__global__ __launch_bounds__(256) void pool_final_kernel(
    const float* __restrict__ partial, float* __restrict__ out) {
  int v = blockIdx.x;
  int tid = threadIdx.x;
  float a0 = 0.f, a1 = 0.f;
#pragma unroll
  for (int c = 0; c < 8; ++c) {
    const float* p = partial + (size_t)(v * 8 + c) * NT;
    a0 += p[tid];
    a1 += p[tid + 256];
  }
  out[v * NT + tid] = a0;
  out[v * NT + tid + 256] = a1;
}

// ---------------------------------------------------------------------------
extern "C" void kernel_launch(void* const* d_in, const int* in_sizes, int n_in,
                              void* d_out, int out_size, void* d_ws, size_t ws_size,
                              hipStream_t stream) {
  const float* self_users = (const float*)d_in[0];
  const float* self_items = (const float*)d_in[1];
  const float* self_mask  = (const float*)d_in[2];
  const float* soc_users  = (const float*)d_in[3];
  const float* soc_items  = (const float*)d_in[4];
  const float* soc_mask   = (const float*)d_in[5];
  const float* ml_user_w  = (const float*)d_in[6];
  const float* ml_user_b  = (const float*)d_in[7];
  const float* ml_w1      = (const float*)d_in[8];
  const float* ml_b1      = (const float*)d_in[9];
  const float* ml_w2      = (const float*)d_in[10];

  char* ws = (char*)d_ws;
  __hip_bfloat16* agg = (__hip_bfloat16*)ws;               // 8448*1024*2 = 17,301,504 B
  __hip_bfloat16* wb  = (__hip_bfloat16*)(ws + 17301504);  // 512*1024*2  =  1,048,576 B
  float* embd         = (float*)(ws + 18350080);           // 8448*512*4  = 17,301,504 B
  float* social_attn  = (float*)(ws + 35651584);           // 256*512*4   =    524,288 B
  float* scores       = (float*)(ws + 36175872);           // 512*4       =      2,048 B
  float* partial      = (float*)(ws + 36177920);           // 16*512*4    =     32,768 B

  hipLaunchKernelGGL(agg_kernel, dim3(M_ROWS), dim3(256), 0, stream,
                     self_users, self_items, self_mask, soc_users, soc_items,
                     soc_mask, agg);
  hipLaunchKernelGGL(cvt_w_kernel, dim3(512), dim3(256), 0, stream, ml_user_w, wb);
  hipLaunchKernelGGL(gemm_bias_relu_kernel, dim3((M_ROWS / GBM) * (NT / GBN)),
                     dim3(256), 0, stream, agg, wb, ml_user_b, embd);
  hipLaunchKernelGGL(attn_kernel, dim3(B_), dim3(256), 0, stream, embd, social_attn);
  hipLaunchKernelGGL(rate_score_kernel, dim3(B_), dim3(256), 0, stream,
                     embd, social_attn, ml_w1, ml_b1, ml_w2, scores);
  hipLaunchKernelGGL(pool_partial_kernel, dim3(16), dim3(256), 0, stream,
                     embd, social_attn, scores, partial);
  hipLaunchKernelGGL(pool_final_kernel, dim3(2), dim3(256), 0, stream,
                     partial, (float*)d_out);
}

// Round 3
// 203.857 us; speedup vs baseline: 1.3497x; 1.2605x over previous
//
#include <hip/hip_runtime.h>
#include <hip/hip_bf16.h>
#include <stdint.h>

#define B_   256
#define S_   32
#define L_   20
#define D_   512
#define IN_  1024
#define M_ROWS 8448   // 256 self rows + 8192 social rows
#define NT   512      // embd dim
#define FBM  48       // fused GEMM M (33 real rows padded to 48)
#define ETS  516      // Etile row stride (f32), padded to break bank alignment

typedef __attribute__((ext_vector_type(4))) float f32x4;
typedef __attribute__((ext_vector_type(8))) short s16x8;

static __device__ __forceinline__ float wave_reduce_sum(float v) {
#pragma unroll
  for (int off = 32; off > 0; off >>= 1) v += __shfl_xor(v, off);
  return v;
}

// ---------------------------------------------------------------------------
// K1: masked mean over L -> agg bf16 [8448][1024]; blocks >= M_ROWS convert
// ml_user_w f32 -> bf16. No barriers: mask loads are block-uniform (s_load).
// ---------------------------------------------------------------------------
__global__ __launch_bounds__(256) void agg_cvt_kernel(
    const float* __restrict__ self_users, const float* __restrict__ self_items,
    const float* __restrict__ self_mask,
    const float* __restrict__ soc_users, const float* __restrict__ soc_items,
    const float* __restrict__ soc_mask,
    const float* __restrict__ w,
    __hip_bfloat16* __restrict__ agg, __hip_bfloat16* __restrict__ wb) {
  int r = blockIdx.x;
  int tid = threadIdx.x;
  if (r >= M_ROWS) {
    // W cast: 128 blocks x 4096 elements
    int base = (r - M_ROWS) * 4096 + tid * 16;
#pragma unroll
    for (int u = 0; u < 4; ++u) {
      f32x4 v = *(const f32x4*)(w + base + u * 4);
      __hip_bfloat16 h[4] = {__float2bfloat16(v[0]), __float2bfloat16(v[1]),
                             __float2bfloat16(v[2]), __float2bfloat16(v[3])};
      *(ushort4*)(wb + base + u * 4) = *(const ushort4*)h;
    }
    return;
  }
  const float *uptr, *iptr, *mptr;
  if (r < B_) {
    uptr = self_users + (size_t)r * (L_ * D_);
    iptr = self_items + (size_t)r * (L_ * D_);
    mptr = self_mask + (size_t)r * L_;
  } else {
    int idx = r - B_;
    uptr = soc_users + (size_t)idx * (L_ * D_);
    iptr = soc_items + (size_t)idx * (L_ * D_);
    mptr = soc_mask + (size_t)idx * L_;
  }
  float mk[L_];
  float msum = 1e-4f;
#pragma unroll
  for (int l = 0; l < L_; ++l) { mk[l] = mptr[l]; msum += mk[l]; }
  float inv = 1.0f / msum;

  const float* base = (tid < 128) ? uptr : iptr;
  int c = (tid & 127) * 4;
  f32x4 acc = {0.f, 0.f, 0.f, 0.f};
#pragma unroll
  for (int l = 0; l < L_; ++l) {
    f32x4 v = *(const f32x4*)(base + (size_t)l * D_ + c);
    acc += v * mk[l];
  }
  acc *= inv;
  __hip_bfloat16 h[4] = {__float2bfloat16(acc[0]), __float2bfloat16(acc[1]),
                         __float2bfloat16(acc[2]), __float2bfloat16(acc[3])};
  size_t o = (size_t)r * IN_ + ((tid < 128) ? 0 : D_) + c;
  *(ushort4*)(agg + o) = *(const ushort4*)h;
}

// ---------------------------------------------------------------------------
// K2: per-user mega-fused kernel. Block b (512 threads, 8 waves):
//   phase 1: GEMM  Et[48][512] = relu(A[48][1024] @ W^T + bias)
//            rows: 0 = self agg row b, 1..32 = social agg rows, 33..47 pad.
//            A,W staged via global_load_lds (linear LDS dest, XOR-swizzled
//            global source granule; reads apply same XOR -> conflict-free).
//   phase 2: attention over rows 1..32 vs row 0, softmax, attn row.
//   phase 3: rate scores: w2 . relu(W1 @ e + b1) for e in {self, attn}.
// Social embd never touches HBM.
// ---------------------------------------------------------------------------
__global__ __launch_bounds__(512) void fused_kernel(
    const __hip_bfloat16* __restrict__ agg, const __hip_bfloat16* __restrict__ wb,
    const float* __restrict__ bias,
    const float* __restrict__ W1, const float* __restrict__ b1,
    const float* __restrict__ w2,
    float* __restrict__ selfE, float* __restrict__ social_attn,
    float* __restrict__ scores) {
  int b = blockIdx.x;
  int tid = threadIdx.x, lane = tid & 63, wid = tid >> 6;

  __shared__ __align__(16) char smem[FBM * ETS * 4];  // 99072 B
  ushort* Asub = (ushort*)smem;        // [48][64] bf16 = 6144 B  (GEMM phase)
  ushort* Wsub = Asub + 3072;          // [512][64] bf16 = 65536 B (GEMM phase)
  float* Et = (float*)smem;            // [48][516] f32 (after GEMM)
  __shared__ float arow[NT];
  __shared__ float sc_sh[S_], att_sh[S_], wpS[8], wpA[8];

  // --- A-stage precompute: slot tid (tid<384): row=tid>>3, granule=tid&7,
  //     source granule XOR-swizzled so linear LDS + swizzled read is bijective.
  int a_row = tid >> 3;                       // 0..47 for tid<384
  int a_g   = (tid & 7) ^ (a_row & 7);
  int growv = (a_row >= 1 && a_row <= 32) ? (B_ + b * S_ + a_row - 1) : b;
  const ushort* aggp = (const ushort*)agg + (size_t)growv * IN_ + a_g * 8;
  const ushort* wbp = (const ushort*)wb;

  f32x4 acc[3][4];
#pragma unroll
  for (int i = 0; i < 3; ++i)
#pragma unroll
    for (int j = 0; j < 4; ++j) acc[i][j] = {0.f, 0.f, 0.f, 0.f};

  for (int kt = 0; kt < IN_; kt += 64) {
    __syncthreads();
    if (tid < 384)  // waves 0..5, uniform
      __builtin_amdgcn_global_load_lds(
          (const __attribute__((address_space(1))) void*)(aggp + kt),
          (__attribute__((address_space(3))) void*)(Asub + tid * 8), 16, 0, 0);
#pragma unroll
    for (int it = 0; it < 8; ++it) {
      int s = it * 512 + tid;               // 0..4095
      int wrow = s >> 3;                    // 0..511
      int wg = (s & 7) ^ (wrow & 7);
      __builtin_amdgcn_global_load_lds(
          (const __attribute__((address_space(1))) void*)(wbp + (size_t)wrow * IN_ + kt + wg * 8),
          (__attribute__((address_space(3))) void*)(Wsub + s * 8), 16, 0, 0);
    }
    __syncthreads();
#pragma unroll
    for (int kk = 0; kk < 64; kk += 32) {
      s16x8 af[3], bf[4];
#pragma unroll
      for (int i = 0; i < 3; ++i) {
        int row = i * 16 + (lane & 15);
        int g = ((kk >> 3) + (lane >> 4)) ^ (row & 7);
        af[i] = *(const s16x8*)(Asub + row * 64 + g * 8);
      }
#pragma unroll
      for (int j = 0; j < 4; ++j) {
        int wrow = wid * 64 + j * 16 + (lane & 15);
        int g = ((kk >> 3) + (lane >> 4)) ^ (wrow & 7);
        bf[j] = *(const s16x8*)(Wsub + wrow * 64 + g * 8);
      }
#pragma unroll
      for (int i = 0; i < 3; ++i)
#pragma unroll
        for (int j = 0; j < 4; ++j)
          acc[i][j] = __builtin_amdgcn_mfma_f32_16x16x32_bf16(af[i], bf[j], acc[i][j], 0, 0, 0);
    }
  }
  __syncthreads();  // staging region now dead; reuse as Et

  // epilogue: bias + relu -> Et. C/D layout col=lane&15, row=(lane>>4)*4+q.
#pragma unroll
  for (int j = 0; j < 4; ++j) {
    int col = wid * 64 + j * 16 + (lane & 15);
    float bv = bias[col];
#pragma unroll
    for (int i = 0; i < 3; ++i) {
#pragma unroll
      for (int q = 0; q < 4; ++q) {
        int row = i * 16 + (lane >> 4) * 4 + q;
        float v = acc[i][j][q] + bv;
        Et[row * ETS + col] = v > 0.f ? v : 0.f;
      }
    }
  }
  __syncthreads();

  // --- attention: dots of rows 1..32 vs row 0 (each wave: 4 rows)
  {
    f32x4 s0 = *(const f32x4*)&Et[lane * 8];
    f32x4 s1 = *(const f32x4*)&Et[lane * 8 + 4];
#pragma unroll
    for (int q = 0; q < 4; ++q) {
      int s = wid * 4 + q + 1;
      f32x4 v0 = *(const f32x4*)&Et[s * ETS + lane * 8];
      f32x4 v1 = *(const f32x4*)&Et[s * ETS + lane * 8 + 4];
      float p = s0[0]*v0[0] + s0[1]*v0[1] + s0[2]*v0[2] + s0[3]*v0[3]
              + s1[0]*v1[0] + s1[1]*v1[1] + s1[2]*v1[2] + s1[3]*v1[3];
      p = wave_reduce_sum(p);
      if (lane == 0) sc_sh[s - 1] = p;
    }
  }
  __syncthreads();
  if (wid == 0) {
    float v = (lane < S_) ? sc_sh[lane] : -3.4e38f;
    float m = v;
#pragma unroll
    for (int off = 16; off > 0; off >>= 1) m = fmaxf(m, __shfl_xor(m, off));
    float e = (lane < S_) ? expf(v - m) : 0.f;
    float sum = e;
#pragma unroll
    for (int off = 16; off > 0; off >>= 1) sum += __shfl_xor(sum, off);
    if (lane < S_) att_sh[lane] = e / sum;
  }
  __syncthreads();
  // weighted sum over social rows; also export self row
  {
    float a = 0.f;
#pragma unroll 8
    for (int s = 1; s <= S_; ++s) a += att_sh[s - 1] * Et[s * ETS + tid];
    arow[tid] = a;
    social_attn[(size_t)b * NT + tid] = a;
    selfE[(size_t)b * NT + tid] = Et[tid];
  }
  __syncthreads();

  // --- rate scores: stream W1 rows (f32, coalesced), dual dot self/attn
  {
    f32x4 es0 = *(const f32x4*)&Et[lane * 8];
    f32x4 es1 = *(const f32x4*)&Et[lane * 8 + 4];
    f32x4 ea0 = *(const f32x4*)&arow[lane * 8];
    f32x4 ea1 = *(const f32x4*)&arow[lane * 8 + 4];
    float accS = 0.f, accA = 0.f;
    for (int r = wid; r < D_; r += 8) {
      const float* wr_ = W1 + (size_t)r * D_ + lane * 8;
      f32x4 w0 = *(const f32x4*)wr_;
      f32x4 w1v = *(const f32x4*)(wr_ + 4);
      float pS = es0[0]*w0[0] + es0[1]*w0[1] + es0[2]*w0[2] + es0[3]*w0[3]
               + es1[0]*w1v[0] + es1[1]*w1v[1] + es1[2]*w1v[2] + es1[3]*w1v[3];
      float pA = ea0[0]*w0[0] + ea0[1]*w0[1] + ea0[2]*w0[2] + ea0[3]*w0[3]
               + ea1[0]*w1v[0] + ea1[1]*w1v[1] + ea1[2]*w1v[2] + ea1[3]*w1v[3];
#pragma unroll
      for (int off = 32; off > 0; off >>= 1) {
        pS += __shfl_xor(pS, off);
        pA += __shfl_xor(pA, off);
      }
      float bv = b1[r], wv = w2[r];
      float tS = pS + bv; tS = tS > 0.f ? tS : 0.f;
      float tA = pA + bv; tA = tA > 0.f ? tA : 0.f;
      accS += wv * tS;
      accA += wv * tA;
    }
    if (lane == 0) { wpS[wid] = accS; wpA[wid] = accA; }
  }
  __syncthreads();
  if (tid == 0) {
    float s = 0.f;
#pragma unroll
    for (int k = 0; k < 8; ++k) s += wpS[k];
    scores[b] = s;
  }
  if (tid == 1) {
    float s = 0.f;
#pragma unroll
    for (int k = 0; k < 8; ++k) s += wpA[k];
    scores[B_ + b] = s;
  }
}

// ---------------------------------------------------------------------------
// K3: batch softmax (recomputed per block) + partial pool over 32 users.
// grid 16: v = blk>>3, chunk = blk&7.
// ---------------------------------------------------------------------------
__global__ __launch_bounds__(256) void pool_partial_kernel(
    const float* __restrict__ selfE, const float* __restrict__ social_attn,
    const float* __restrict__ scores, float* __restrict__ partial) {
  int v = blockIdx.x >> 3;
  int chunk = blockIdx.x & 7;
  const float* E = v ? social_attn : selfE;
  const float* sc = scores + v * B_;
  __shared__ float att[B_];
  __shared__ float red[8];
  int tid = threadIdx.x, lane = tid & 63, wid = tid >> 6;
  float s = sc[tid];
  float m = s;
#pragma unroll
  for (int off = 32; off > 0; off >>= 1) m = fmaxf(m, __shfl_xor(m, off));
  if (lane == 0) red[wid] = m;
  __syncthreads();
  m = fmaxf(fmaxf(red[0], red[1]), fmaxf(red[2], red[3]));
  float ev = expf(s - m);
  float sum = wave_reduce_sum(ev);
  if (lane == 0) red[4 + wid] = sum;
  __syncthreads();
  sum = red[4] + red[5] + red[6] + red[7];
  att[tid] = ev / sum;
  __syncthreads();
  float a0 = 0.f, a1 = 0.f;
#pragma unroll 8
  for (int q = 0; q < 32; ++q) {
    int b = chunk * 32 + q;
    float w = att[b];
    a0 += w * E[(size_t)b * NT + tid];
    a1 += w * E[(size_t)b * NT + tid + 256];
  }
  partial[(size_t)blockIdx.x * NT + tid] = a0;
  partial[(size_t)blockIdx.x * NT + tid + 256] = a1;
}

// ---------------------------------------------------------------------------
// K4: final reduce of 8 partials per v -> out[v][512]
// ---------------------------------------------------------------------------
__global__ __launch_bounds__(256) void pool_final_kernel(
    const float* __restrict__ partial, float* __restrict__ out) {
  int v = blockIdx.x;
  int tid = threadIdx.x;
  float a0 = 0.f, a1 = 0.f;
#pragma unroll
  for (int c = 0; c < 8; ++c) {
    const float* p = partial + (size_t)(v * 8 + c) * NT;
    a0 += p[tid];
    a1 += p[tid + 256];
  }
  out[v * NT + tid] = a0;
  out[v * NT + tid + 256] = a1;
}

// ---------------------------------------------------------------------------
extern "C" void kernel_launch(void* const* d_in, const int* in_sizes, int n_in,
                              void* d_out, int out_size, void* d_ws, size_t ws_size,
                              hipStream_t stream) {
  const float* self_users = (const float*)d_in[0];
  const float* self_items = (const float*)d_in[1];
  const float* self_mask  = (const float*)d_in[2];
  const float* soc_users  = (const float*)d_in[3];
  const float* soc_items  = (const float*)d_in[4];
  const float* soc_mask   = (const float*)d_in[5];
  const float* ml_user_w  = (const float*)d_in[6];
  const float* ml_user_b  = (const float*)d_in[7];
  const float* ml_w1      = (const float*)d_in[8];
  const float* ml_b1      = (const float*)d_in[9];
  const float* ml_w2      = (const float*)d_in[10];

  char* ws = (char*)d_ws;
  __hip_bfloat16* agg = (__hip_bfloat16*)ws;               // 17,301,504 B
  __hip_bfloat16* wb  = (__hip_bfloat16*)(ws + 17301504);  //  1,048,576 B
  float* selfE        = (float*)(ws + 18350080);           //    524,288 B
  float* social_attn  = (float*)(ws + 18874368);           //    524,288 B
  float* scores       = (float*)(ws + 19398656);           //      2,048 B
  float* partial      = (float*)(ws + 19400704);           //     32,768 B

  hipLaunchKernelGGL(agg_cvt_kernel, dim3(M_ROWS + 128), dim3(256), 0, stream,
                     self_users, self_items, self_mask, soc_users, soc_items,
                     soc_mask, ml_user_w, agg, wb);
  hipLaunchKernelGGL(fused_kernel, dim3(B_), dim3(512), 0, stream,
                     agg, wb, ml_user_b, ml_w1, ml_b1, ml_w2,
                     selfE, social_attn, scores);
  hipLaunchKernelGGL(pool_partial_kernel, dim3(16), dim3(256), 0, stream,
                     selfE, social_attn, scores, partial);
  hipLaunchKernelGGL(pool_final_kernel, dim3(2), dim3(256), 0, stream,
                     partial, (float*)d_out);
}

// Round 4
// 202.989 us; speedup vs baseline: 1.3555x; 1.0043x over previous
//
#include <hip/hip_runtime.h>
#include <hip/hip_bf16.h>
#include <stdint.h>

#define B_   256
#define S_   32
#define L_   20
#define D_   512
#define IN_  1024
#define M_ROWS 8448   // 256 self rows + 8192 social rows
#define NT   512      // embd dim
#define FBM  48       // fused GEMM M (33 real rows padded to 48)
#define ETS  516      // Etile row stride (f32), padded to break bank alignment

typedef __attribute__((ext_vector_type(4))) float f32x4;
typedef __attribute__((ext_vector_type(8))) short s16x8;

static __device__ __forceinline__ float wave_reduce_sum(float v) {
#pragma unroll
  for (int off = 32; off > 0; off >>= 1) v += __shfl_xor(v, off);
  return v;
}

// ---------------------------------------------------------------------------
// K1: masked mean over L -> agg bf16 [8448][1024]; blocks >= M_ROWS convert
// ml_user_w f32 -> bf16.
// MLP fix: preload all 20 f32x4 into a statically-indexed register array so
// 20 global_load_dwordx4 are in flight per thread (was: 1, VGPR-starved).
// ---------------------------------------------------------------------------
__global__ __launch_bounds__(256) void agg_cvt_kernel(
    const float* __restrict__ self_users, const float* __restrict__ self_items,
    const float* __restrict__ self_mask,
    const float* __restrict__ soc_users, const float* __restrict__ soc_items,
    const float* __restrict__ soc_mask,
    const float* __restrict__ w,
    __hip_bfloat16* __restrict__ agg, __hip_bfloat16* __restrict__ wb) {
  int r = blockIdx.x;
  int tid = threadIdx.x;
  if (r >= M_ROWS) {
    // W cast: 128 blocks x 4096 elements
    int base = (r - M_ROWS) * 4096 + tid * 16;
#pragma unroll
    for (int u = 0; u < 4; ++u) {
      f32x4 v = *(const f32x4*)(w + base + u * 4);
      __hip_bfloat16 h[4] = {__float2bfloat16(v[0]), __float2bfloat16(v[1]),
                             __float2bfloat16(v[2]), __float2bfloat16(v[3])};
      *(ushort4*)(wb + base + u * 4) = *(const ushort4*)h;
    }
    return;
  }
  const float *uptr, *iptr, *mptr;
  if (r < B_) {
    uptr = self_users + (size_t)r * (L_ * D_);
    iptr = self_items + (size_t)r * (L_ * D_);
    mptr = self_mask + (size_t)r * L_;
  } else {
    int idx = r - B_;
    uptr = soc_users + (size_t)idx * (L_ * D_);
    iptr = soc_items + (size_t)idx * (L_ * D_);
    mptr = soc_mask + (size_t)idx * L_;
  }

  // Issue ALL data loads first — 20 independent dwordx4 per thread in flight.
  const float* base = ((tid < 128) ? uptr : iptr) + (tid & 127) * 4;
  f32x4 v[L_];
#pragma unroll
  for (int l = 0; l < L_; ++l)
    v[l] = *(const f32x4*)(base + (size_t)l * D_);

  // Mask (block-uniform scalar loads) overlaps with the loads above.
  float mk[L_];
  float msum = 1e-4f;
#pragma unroll
  for (int l = 0; l < L_; ++l) { mk[l] = mptr[l]; msum += mk[l]; }
  float inv = 1.0f / msum;

  f32x4 acc = {0.f, 0.f, 0.f, 0.f};
#pragma unroll
  for (int l = 0; l < L_; ++l) acc += v[l] * mk[l];
  acc *= inv;

  __hip_bfloat16 h[4] = {__float2bfloat16(acc[0]), __float2bfloat16(acc[1]),
                         __float2bfloat16(acc[2]), __float2bfloat16(acc[3])};
  size_t o = (size_t)r * IN_ + ((tid < 128) ? 0 : D_) + (tid & 127) * 4;
  *(ushort4*)(agg + o) = *(const ushort4*)h;
}

// ---------------------------------------------------------------------------
// K2: per-user mega-fused kernel. Block b (512 threads, 8 waves):
//   phase 1: GEMM  Et[48][512] = relu(A[48][1024] @ W^T + bias)
//            rows: 0 = self agg row b, 1..32 = social agg rows, 33..47 pad.
//   phase 2: attention over rows 1..32 vs row 0, softmax, attn row.
//   phase 3: rate scores: w2 . relu(W1 @ e + b1) for e in {self, attn}.
// Social embd never touches HBM.
// ---------------------------------------------------------------------------
__global__ __launch_bounds__(512) void fused_kernel(
    const __hip_bfloat16* __restrict__ agg, const __hip_bfloat16* __restrict__ wb,
    const float* __restrict__ bias,
    const float* __restrict__ W1, const float* __restrict__ b1,
    const float* __restrict__ w2,
    float* __restrict__ selfE, float* __restrict__ social_attn,
    float* __restrict__ scores) {
  int b = blockIdx.x;
  int tid = threadIdx.x, lane = tid & 63, wid = tid >> 6;

  __shared__ __align__(16) char smem[FBM * ETS * 4];  // 99072 B
  ushort* Asub = (ushort*)smem;        // [48][64] bf16 = 6144 B  (GEMM phase)
  ushort* Wsub = Asub + 3072;          // [512][64] bf16 = 65536 B (GEMM phase)
  float* Et = (float*)smem;            // [48][516] f32 (after GEMM)
  __shared__ float arow[NT];
  __shared__ float sc_sh[S_], att_sh[S_], wpS[8], wpA[8];

  int a_row = tid >> 3;                       // 0..47 for tid<384
  int a_g   = (tid & 7) ^ (a_row & 7);
  int growv = (a_row >= 1 && a_row <= 32) ? (B_ + b * S_ + a_row - 1) : b;
  const ushort* aggp = (const ushort*)agg + (size_t)growv * IN_ + a_g * 8;
  const ushort* wbp = (const ushort*)wb;

  f32x4 acc[3][4];
#pragma unroll
  for (int i = 0; i < 3; ++i)
#pragma unroll
    for (int j = 0; j < 4; ++j) acc[i][j] = {0.f, 0.f, 0.f, 0.f};

  for (int kt = 0; kt < IN_; kt += 64) {
    __syncthreads();
    if (tid < 384)  // waves 0..5, uniform
      __builtin_amdgcn_global_load_lds(
          (const __attribute__((address_space(1))) void*)(aggp + kt),
          (__attribute__((address_space(3))) void*)(Asub + tid * 8), 16, 0, 0);
#pragma unroll
    for (int it = 0; it < 8; ++it) {
      int s = it * 512 + tid;               // 0..4095
      int wrow = s >> 3;                    // 0..511
      int wg = (s & 7) ^ (wrow & 7);
      __builtin_amdgcn_global_load_lds(
          (const __attribute__((address_space(1))) void*)(wbp + (size_t)wrow * IN_ + kt + wg * 8),
          (__attribute__((address_space(3))) void*)(Wsub + s * 8), 16, 0, 0);
    }
    __syncthreads();
#pragma unroll
    for (int kk = 0; kk < 64; kk += 32) {
      s16x8 af[3], bf[4];
#pragma unroll
      for (int i = 0; i < 3; ++i) {
        int row = i * 16 + (lane & 15);
        int g = ((kk >> 3) + (lane >> 4)) ^ (row & 7);
        af[i] = *(const s16x8*)(Asub + row * 64 + g * 8);
      }
#pragma unroll
      for (int j = 0; j < 4; ++j) {
        int wrow = wid * 64 + j * 16 + (lane & 15);
        int g = ((kk >> 3) + (lane >> 4)) ^ (wrow & 7);
        bf[j] = *(const s16x8*)(Wsub + wrow * 64 + g * 8);
      }
#pragma unroll
      for (int i = 0; i < 3; ++i)
#pragma unroll
        for (int j = 0; j < 4; ++j)
          acc[i][j] = __builtin_amdgcn_mfma_f32_16x16x32_bf16(af[i], bf[j], acc[i][j], 0, 0, 0);
    }
  }
  __syncthreads();  // staging region now dead; reuse as Et

  // epilogue: bias + relu -> Et. C/D layout col=lane&15, row=(lane>>4)*4+q.
#pragma unroll
  for (int j = 0; j < 4; ++j) {
    int col = wid * 64 + j * 16 + (lane & 15);
    float bv = bias[col];
#pragma unroll
    for (int i = 0; i < 3; ++i) {
#pragma unroll
      for (int q = 0; q < 4; ++q) {
        int row = i * 16 + (lane >> 4) * 4 + q;
        float v = acc[i][j][q] + bv;
        Et[row * ETS + col] = v > 0.f ? v : 0.f;
      }
    }
  }
  __syncthreads();

  // --- attention: dots of rows 1..32 vs row 0 (each wave: 4 rows)
  {
    f32x4 s0 = *(const f32x4*)&Et[lane * 8];
    f32x4 s1 = *(const f32x4*)&Et[lane * 8 + 4];
#pragma unroll
    for (int q = 0; q < 4; ++q) {
      int s = wid * 4 + q + 1;
      f32x4 v0 = *(const f32x4*)&Et[s * ETS + lane * 8];
      f32x4 v1 = *(const f32x4*)&Et[s * ETS + lane * 8 + 4];
      float p = s0[0]*v0[0] + s0[1]*v0[1] + s0[2]*v0[2] + s0[3]*v0[3]
              + s1[0]*v1[0] + s1[1]*v1[1] + s1[2]*v1[2] + s1[3]*v1[3];
      p = wave_reduce_sum(p);
      if (lane == 0) sc_sh[s - 1] = p;
    }
  }
  __syncthreads();
  if (wid == 0) {
    float v = (lane < S_) ? sc_sh[lane] : -3.4e38f;
    float m = v;
#pragma unroll
    for (int off = 16; off > 0; off >>= 1) m = fmaxf(m, __shfl_xor(m, off));
    float e = (lane < S_) ? expf(v - m) : 0.f;
    float sum = e;
#pragma unroll
    for (int off = 16; off > 0; off >>= 1) sum += __shfl_xor(sum, off);
    if (lane < S_) att_sh[lane] = e / sum;
  }
  __syncthreads();
  // weighted sum over social rows; also export self row
  {
    float a = 0.f;
#pragma unroll 8
    for (int s = 1; s <= S_; ++s) a += att_sh[s - 1] * Et[s * ETS + tid];
    arow[tid] = a;
    social_attn[(size_t)b * NT + tid] = a;
    selfE[(size_t)b * NT + tid] = Et[tid];
  }
  __syncthreads();

  // --- rate scores: stream W1 rows (f32, coalesced), dual dot self/attn
  {
    f32x4 es0 = *(const f32x4*)&Et[lane * 8];
    f32x4 es1 = *(const f32x4*)&Et[lane * 8 + 4];
    f32x4 ea0 = *(const f32x4*)&arow[lane * 8];
    f32x4 ea1 = *(const f32x4*)&arow[lane * 8 + 4];
    float accS = 0.f, accA = 0.f;
    for (int r = wid; r < D_; r += 8) {
      const float* wr_ = W1 + (size_t)r * D_ + lane * 8;
      f32x4 w0 = *(const f32x4*)wr_;
      f32x4 w1v = *(const f32x4*)(wr_ + 4);
      float pS = es0[0]*w0[0] + es0[1]*w0[1] + es0[2]*w0[2] + es0[3]*w0[3]
               + es1[0]*w1v[0] + es1[1]*w1v[1] + es1[2]*w1v[2] + es1[3]*w1v[3];
      float pA = ea0[0]*w0[0] + ea0[1]*w0[1] + ea0[2]*w0[2] + ea0[3]*w0[3]
               + ea1[0]*w1v[0] + ea1[1]*w1v[1] + ea1[2]*w1v[2] + ea1[3]*w1v[3];
#pragma unroll
      for (int off = 32; off > 0; off >>= 1) {
        pS += __shfl_xor(pS, off);
        pA += __shfl_xor(pA, off);
      }
      float bv = b1[r], wv = w2[r];
      float tS = pS + bv; tS = tS > 0.f ? tS : 0.f;
      float tA = pA + bv; tA = tA > 0.f ? tA : 0.f;
      accS += wv * tS;
      accA += wv * tA;
    }
    if (lane == 0) { wpS[wid] = accS; wpA[wid] = accA; }
  }
  __syncthreads();
  if (tid == 0) {
    float s = 0.f;
#pragma unroll
    for (int k = 0; k < 8; ++k) s += wpS[k];
    scores[b] = s;
  }
  if (tid == 1) {
    float s = 0.f;
#pragma unroll
    for (int k = 0; k < 8; ++k) s += wpA[k];
    scores[B_ + b] = s;
  }
}

// ---------------------------------------------------------------------------
// K3: batch softmax (recomputed per block) + partial pool over 32 users.
// grid 16: v = blk>>3, chunk = blk&7.
// ---------------------------------------------------------------------------
__global__ __launch_bounds__(256) void pool_partial_kernel(
    const float* __restrict__ selfE, const float* __restrict__ social_attn,
    const float* __restrict__ scores, float* __restrict__ partial) {
  int v = blockIdx.x >> 3;
  int chunk = blockIdx.x & 7;
  const float* E = v ? social_attn : selfE;
  const float* sc = scores + v * B_;
  __shared__ float att[B_];
  __shared__ float red[8];
  int tid = threadIdx.x, lane = tid & 63, wid = tid >> 6;
  float s = sc[tid];
  float m = s;
#pragma unroll
  for (int off = 32; off > 0; off >>= 1) m = fmaxf(m, __shfl_xor(m, off));
  if (lane == 0) red[wid] = m;
  __syncthreads();
  m = fmaxf(fmaxf(red[0], red[1]), fmaxf(red[2], red[3]));
  float ev = expf(s - m);
  float sum = wave_reduce_sum(ev);
  if (lane == 0) red[4 + wid] = sum;
  __syncthreads();
  sum = red[4] + red[5] + red[6] + red[7];
  att[tid] = ev / sum;
  __syncthreads();
  float a0 = 0.f, a1 = 0.f;
#pragma unroll 8
  for (int q = 0; q < 32; ++q) {
    int b = chunk * 32 + q;
    float w = att[b];
    a0 += w * E[(size_t)b * NT + tid];
    a1 += w * E[(size_t)b * NT + tid + 256];
  }
  partial[(size_t)blockIdx.x * NT + tid] = a0;
  partial[(size_t)blockIdx.x * NT + tid + 256] = a1;
}

// ---------------------------------------------------------------------------
// K4: final reduce of 8 partials per v -> out[v][512]
// ---------------------------------------------------------------------------
__global__ __launch_bounds__(256) void pool_final_kernel(
    const float* __restrict__ partial, float* __restrict__ out) {
  int v = blockIdx.x;
  int tid = threadIdx.x;
  float a0 = 0.f, a1 = 0.f;
#pragma unroll
  for (int c = 0; c < 8; ++c) {
    const float* p = partial + (size_t)(v * 8 + c) * NT;
    a0 += p[tid];
    a1 += p[tid + 256];
  }
  out[v * NT + tid] = a0;
  out[v * NT + tid + 256] = a1;
}

// ---------------------------------------------------------------------------
extern "C" void kernel_launch(void* const* d_in, const int* in_sizes, int n_in,
                              void* d_out, int out_size, void* d_ws, size_t ws_size,
                              hipStream_t stream) {
  const float* self_users = (const float*)d_in[0];
  const float* self_items = (const float*)d_in[1];
  const float* self_mask  = (const float*)d_in[2];
  const float* soc_users  = (const float*)d_in[3];
  const float* soc_items  = (const float*)d_in[4];
  const float* soc_mask   = (const float*)d_in[5];
  const float* ml_user_w  = (const float*)d_in[6];
  const float* ml_user_b  = (const float*)d_in[7];
  const float* ml_w1      = (const float*)d_in[8];
  const float* ml_b1      = (const float*)d_in[9];
  const float* ml_w2      = (const float*)d_in[10];

  char* ws = (char*)d_ws;
  __hip_bfloat16* agg = (__hip_bfloat16*)ws;               // 17,301,504 B
  __hip_bfloat16* wb  = (__hip_bfloat16*)(ws + 17301504);  //  1,048,576 B
  float* selfE        = (float*)(ws + 18350080);           //    524,288 B
  float* social_attn  = (float*)(ws + 18874368);           //    524,288 B
  float* scores       = (float*)(ws + 19398656);           //      2,048 B
  float* partial      = (float*)(ws + 19400704);           //     32,768 B

  hipLaunchKernelGGL(agg_cvt_kernel, dim3(M_ROWS + 128), dim3(256), 0, stream,
                     self_users, self_items, self_mask, soc_users, soc_items,
                     soc_mask, ml_user_w, agg, wb);
  hipLaunchKernelGGL(fused_kernel, dim3(B_), dim3(512), 0, stream,
                     agg, wb, ml_user_b, ml_w1, ml_b1, ml_w2,
                     selfE, social_attn, scores);
  hipLaunchKernelGGL(pool_partial_kernel, dim3(16), dim3(256), 0, stream,
                     selfE, social_attn, scores, partial);
  hipLaunchKernelGGL(pool_final_kernel, dim3(2), dim3(256), 0, stream,
                     partial, (float*)d_out);
}

// Round 5
// 198.287 us; speedup vs baseline: 1.3877x; 1.0237x over previous
//
#include <hip/hip_runtime.h>
#include <hip/hip_bf16.h>
#include <stdint.h>

#define B_   256
#define S_   32
#define L_   20
#define D_   512
#define IN_  1024
#define M_ROWS 8448   // 256 self rows + 8192 social rows
#define NT   512      // embd dim
#define FBM  48       // fused GEMM M (33 real rows padded to 48)
#define ETS  516      // Etile row stride (f32), padded to break bank alignment

typedef __attribute__((ext_vector_type(4))) float f32x4;
typedef __attribute__((ext_vector_type(8))) short s16x8;

static __device__ __forceinline__ float wave_reduce_sum(float v) {
#pragma unroll
  for (int off = 32; off > 0; off >>= 1) v += __shfl_xor(v, off);
  return v;
}

// ---------------------------------------------------------------------------
// K1: masked mean over L -> agg bf16 [8448][1024].
// One block per (row, array) pair: stages the contiguous 40KB L*D row block
// into LDS via global_load_lds (fire-and-forget DMA — no VGPR deps, compiler
// cannot serialize the stream), then reduces from LDS.
// 40KB LDS -> 4 blocks/CU: while one block drains, three keep issuing.
// Blocks >= 2*M_ROWS convert ml_user_w f32 -> bf16.
// ---------------------------------------------------------------------------
__global__ __launch_bounds__(256) void agg_cvt_kernel(
    const float* __restrict__ self_users, const float* __restrict__ self_items,
    const float* __restrict__ self_mask,
    const float* __restrict__ soc_users, const float* __restrict__ soc_items,
    const float* __restrict__ soc_mask,
    const float* __restrict__ w,
    __hip_bfloat16* __restrict__ agg, __hip_bfloat16* __restrict__ wb) {
  int r = blockIdx.x;
  int tid = threadIdx.x;
  if (r >= 2 * M_ROWS) {
    // W cast: 128 blocks x 4096 elements
    int base = (r - 2 * M_ROWS) * 4096 + tid * 16;
#pragma unroll
    for (int u = 0; u < 4; ++u) {
      f32x4 v = *(const f32x4*)(w + base + u * 4);
      __hip_bfloat16 h[4] = {__float2bfloat16(v[0]), __float2bfloat16(v[1]),
                             __float2bfloat16(v[2]), __float2bfloat16(v[3])};
      *(ushort4*)(wb + base + u * 4) = *(const ushort4*)h;
    }
    return;
  }
  __shared__ __align__(16) float rowbuf[L_ * D_];  // 40 KB
  int arr = r & 1;          // 0 = users, 1 = items
  int row = r >> 1;         // 0..8447
  const float* src;
  const float* mptr;
  if (row < B_) {
    src = (arr ? self_items : self_users) + (size_t)row * (L_ * D_);
    mptr = self_mask + (size_t)row * L_;
  } else {
    int idx = row - B_;
    src = (arr ? soc_items : soc_users) + (size_t)idx * (L_ * D_);
    mptr = soc_mask + (size_t)idx * L_;
  }
  // Stage 40KB contiguous: 10 x 4KB wave-linear issues, all in flight.
#pragma unroll
  for (int k = 0; k < 10; ++k) {
    int off = (k * 256 + tid) * 4;  // floats; 16B per lane, linear
    __builtin_amdgcn_global_load_lds(
        (const __attribute__((address_space(1))) void*)(src + off),
        (__attribute__((address_space(3))) void*)(rowbuf + off), 16, 0, 0);
  }
  // Mask (block-uniform scalar loads) overlaps with the DMA.
  float mk[L_];
  float msum = 1e-4f;
#pragma unroll
  for (int l = 0; l < L_; ++l) { mk[l] = mptr[l]; msum += mk[l]; }
  float inv = 1.0f / msum;
  __syncthreads();  // vmcnt(0) drain + barrier -> rowbuf ready

  float a0 = 0.f, a1 = 0.f;
#pragma unroll
  for (int l = 0; l < L_; ++l) {
    float2 v = *(const float2*)&rowbuf[l * D_ + tid * 2];
    a0 += mk[l] * v.x;
    a1 += mk[l] * v.y;
  }
  a0 *= inv;
  a1 *= inv;
  __hip_bfloat16 h[2] = {__float2bfloat16(a0), __float2bfloat16(a1)};
  *(ushort2*)(agg + (size_t)row * IN_ + arr * D_ + tid * 2) = *(const ushort2*)h;
}

// ---------------------------------------------------------------------------
// K2: per-user mega-fused kernel. Block b (512 threads, 8 waves):
//   phase 1: GEMM  Et[48][512] = relu(A[48][1024] @ W^T + bias)
//            rows: 0 = self agg row b, 1..32 = social agg rows, 33..47 pad.
//   phase 2: attention over rows 1..32 vs row 0, softmax, attn row.
//   phase 3: rate scores: w2 . relu(W1 @ e + b1) for e in {self, attn}.
// Social embd never touches HBM.
// ---------------------------------------------------------------------------
__global__ __launch_bounds__(512) void fused_kernel(
    const __hip_bfloat16* __restrict__ agg, const __hip_bfloat16* __restrict__ wb,
    const float* __restrict__ bias,
    const float* __restrict__ W1, const float* __restrict__ b1,
    const float* __restrict__ w2,
    float* __restrict__ selfE, float* __restrict__ social_attn,
    float* __restrict__ scores) {
  int b = blockIdx.x;
  int tid = threadIdx.x, lane = tid & 63, wid = tid >> 6;

  __shared__ __align__(16) char smem[FBM * ETS * 4];  // 99072 B
  ushort* Asub = (ushort*)smem;        // [48][64] bf16 = 6144 B  (GEMM phase)
  ushort* Wsub = Asub + 3072;          // [512][64] bf16 = 65536 B (GEMM phase)
  float* Et = (float*)smem;            // [48][516] f32 (after GEMM)
  __shared__ float arow[NT];
  __shared__ float sc_sh[S_], att_sh[S_], wpS[8], wpA[8];

  int a_row = tid >> 3;                       // 0..47 for tid<384
  int a_g   = (tid & 7) ^ (a_row & 7);
  int growv = (a_row >= 1 && a_row <= 32) ? (B_ + b * S_ + a_row - 1) : b;
  const ushort* aggp = (const ushort*)agg + (size_t)growv * IN_ + a_g * 8;
  const ushort* wbp = (const ushort*)wb;

  f32x4 acc[3][4];
#pragma unroll
  for (int i = 0; i < 3; ++i)
#pragma unroll
    for (int j = 0; j < 4; ++j) acc[i][j] = {0.f, 0.f, 0.f, 0.f};

  for (int kt = 0; kt < IN_; kt += 64) {
    __syncthreads();
    if (tid < 384)  // waves 0..5, uniform
      __builtin_amdgcn_global_load_lds(
          (const __attribute__((address_space(1))) void*)(aggp + kt),
          (__attribute__((address_space(3))) void*)(Asub + tid * 8), 16, 0, 0);
#pragma unroll
    for (int it = 0; it < 8; ++it) {
      int s = it * 512 + tid;               // 0..4095
      int wrow = s >> 3;                    // 0..511
      int wg = (s & 7) ^ (wrow & 7);
      __builtin_amdgcn_global_load_lds(
          (const __attribute__((address_space(1))) void*)(wbp + (size_t)wrow * IN_ + kt + wg * 8),
          (__attribute__((address_space(3))) void*)(Wsub + s * 8), 16, 0, 0);
    }
    __syncthreads();
#pragma unroll
    for (int kk = 0; kk < 64; kk += 32) {
      s16x8 af[3], bf[4];
#pragma unroll
      for (int i = 0; i < 3; ++i) {
        int row = i * 16 + (lane & 15);
        int g = ((kk >> 3) + (lane >> 4)) ^ (row & 7);
        af[i] = *(const s16x8*)(Asub + row * 64 + g * 8);
      }
#pragma unroll
      for (int j = 0; j < 4; ++j) {
        int wrow = wid * 64 + j * 16 + (lane & 15);
        int g = ((kk >> 3) + (lane >> 4)) ^ (wrow & 7);
        bf[j] = *(const s16x8*)(Wsub + wrow * 64 + g * 8);
      }
#pragma unroll
      for (int i = 0; i < 3; ++i)
#pragma unroll
        for (int j = 0; j < 4; ++j)
          acc[i][j] = __builtin_amdgcn_mfma_f32_16x16x32_bf16(af[i], bf[j], acc[i][j], 0, 0, 0);
    }
  }
  __syncthreads();  // staging region now dead; reuse as Et

  // epilogue: bias + relu -> Et. C/D layout col=lane&15, row=(lane>>4)*4+q.
#pragma unroll
  for (int j = 0; j < 4; ++j) {
    int col = wid * 64 + j * 16 + (lane & 15);
    float bv = bias[col];
#pragma unroll
    for (int i = 0; i < 3; ++i) {
#pragma unroll
      for (int q = 0; q < 4; ++q) {
        int row = i * 16 + (lane >> 4) * 4 + q;
        float v = acc[i][j][q] + bv;
        Et[row * ETS + col] = v > 0.f ? v : 0.f;
      }
    }
  }
  __syncthreads();

  // --- attention: dots of rows 1..32 vs row 0 (each wave: 4 rows)
  {
    f32x4 s0 = *(const f32x4*)&Et[lane * 8];
    f32x4 s1 = *(const f32x4*)&Et[lane * 8 + 4];
#pragma unroll
    for (int q = 0; q < 4; ++q) {
      int s = wid * 4 + q + 1;
      f32x4 v0 = *(const f32x4*)&Et[s * ETS + lane * 8];
      f32x4 v1 = *(const f32x4*)&Et[s * ETS + lane * 8 + 4];
      float p = s0[0]*v0[0] + s0[1]*v0[1] + s0[2]*v0[2] + s0[3]*v0[3]
              + s1[0]*v1[0] + s1[1]*v1[1] + s1[2]*v1[2] + s1[3]*v1[3];
      p = wave_reduce_sum(p);
      if (lane == 0) sc_sh[s - 1] = p;
    }
  }
  __syncthreads();
  if (wid == 0) {
    float v = (lane < S_) ? sc_sh[lane] : -3.4e38f;
    float m = v;
#pragma unroll
    for (int off = 16; off > 0; off >>= 1) m = fmaxf(m, __shfl_xor(m, off));
    float e = (lane < S_) ? expf(v - m) : 0.f;
    float sum = e;
#pragma unroll
    for (int off = 16; off > 0; off >>= 1) sum += __shfl_xor(sum, off);
    if (lane < S_) att_sh[lane] = e / sum;
  }
  __syncthreads();
  // weighted sum over social rows; also export self row
  {
    float a = 0.f;
#pragma unroll 8
    for (int s = 1; s <= S_; ++s) a += att_sh[s - 1] * Et[s * ETS + tid];
    arow[tid] = a;
    social_attn[(size_t)b * NT + tid] = a;
    selfE[(size_t)b * NT + tid] = Et[tid];
  }
  __syncthreads();

  // --- rate scores: stream W1 rows (f32, coalesced), dual dot self/attn
  {
    f32x4 es0 = *(const f32x4*)&Et[lane * 8];
    f32x4 es1 = *(const f32x4*)&Et[lane * 8 + 4];
    f32x4 ea0 = *(const f32x4*)&arow[lane * 8];
    f32x4 ea1 = *(const f32x4*)&arow[lane * 8 + 4];
    float accS = 0.f, accA = 0.f;
    for (int r = wid; r < D_; r += 8) {
      const float* wr_ = W1 + (size_t)r * D_ + lane * 8;
      f32x4 w0 = *(const f32x4*)wr_;
      f32x4 w1v = *(const f32x4*)(wr_ + 4);
      float pS = es0[0]*w0[0] + es0[1]*w0[1] + es0[2]*w0[2] + es0[3]*w0[3]
               + es1[0]*w1v[0] + es1[1]*w1v[1] + es1[2]*w1v[2] + es1[3]*w1v[3];
      float pA = ea0[0]*w0[0] + ea0[1]*w0[1] + ea0[2]*w0[2] + ea0[3]*w0[3]
               + ea1[0]*w1v[0] + ea1[1]*w1v[1] + ea1[2]*w1v[2] + ea1[3]*w1v[3];
#pragma unroll
      for (int off = 32; off > 0; off >>= 1) {
        pS += __shfl_xor(pS, off);
        pA += __shfl_xor(pA, off);
      }
      float bv = b1[r], wv = w2[r];
      float tS = pS + bv; tS = tS > 0.f ? tS : 0.f;
      float tA = pA + bv; tA = tA > 0.f ? tA : 0.f;
      accS += wv * tS;
      accA += wv * tA;
    }
    if (lane == 0) { wpS[wid] = accS; wpA[wid] = accA; }
  }
  __syncthreads();
  if (tid == 0) {
    float s = 0.f;
#pragma unroll
    for (int k = 0; k < 8; ++k) s += wpS[k];
    scores[b] = s;
  }
  if (tid == 1) {
    float s = 0.f;
#pragma unroll
    for (int k = 0; k < 8; ++k) s += wpA[k];
    scores[B_ + b] = s;
  }
}

// ---------------------------------------------------------------------------
// K3: batch softmax (recomputed per block) + partial pool over 32 users.
// grid 16: v = blk>>3, chunk = blk&7.
// ---------------------------------------------------------------------------
__global__ __launch_bounds__(256) void pool_partial_kernel(
    const float* __restrict__ selfE, const float* __restrict__ social_attn,
    const float* __restrict__ scores, float* __restrict__ partial) {
  int v = blockIdx.x >> 3;
  int chunk = blockIdx.x & 7;
  const float* E = v ? social_attn : selfE;
  const float* sc = scores + v * B_;
  __shared__ float att[B_];
  __shared__ float red[8];
  int tid = threadIdx.x, lane = tid & 63, wid = tid >> 6;
  float s = sc[tid];
  float m = s;
#pragma unroll
  for (int off = 32; off > 0; off >>= 1) m = fmaxf(m, __shfl_xor(m, off));
  if (lane == 0) red[wid] = m;
  __syncthreads();
  m = fmaxf(fmaxf(red[0], red[1]), fmaxf(red[2], red[3]));
  float ev = expf(s - m);
  float sum = wave_reduce_sum(ev);
  if (lane == 0) red[4 + wid] = sum;
  __syncthreads();
  sum = red[4] + red[5] + red[6] + red[7];
  att[tid] = ev / sum;
  __syncthreads();
  float a0 = 0.f, a1 = 0.f;
#pragma unroll 8
  for (int q = 0; q < 32; ++q) {
    int b = chunk * 32 + q;
    float w = att[b];
    a0 += w * E[(size_t)b * NT + tid];
    a1 += w * E[(size_t)b * NT + tid + 256];
  }
  partial[(size_t)blockIdx.x * NT + tid] = a0;
  partial[(size_t)blockIdx.x * NT + tid + 256] = a1;
}

// ---------------------------------------------------------------------------
// K4: final reduce of 8 partials per v -> out[v][512]
// ---------------------------------------------------------------------------
__global__ __launch_bounds__(256) void pool_final_kernel(
    const float* __restrict__ partial, float* __restrict__ out) {
  int v = blockIdx.x;
  int tid = threadIdx.x;
  float a0 = 0.f, a1 = 0.f;
#pragma unroll
  for (int c = 0; c < 8; ++c) {
    const float* p = partial + (size_t)(v * 8 + c) * NT;
    a0 += p[tid];
    a1 += p[tid + 256];
  }
  out[v * NT + tid] = a0;
  out[v * NT + tid + 256] = a1;
}

// ---------------------------------------------------------------------------
extern "C" void kernel_launch(void* const* d_in, const int* in_sizes, int n_in,
                              void* d_out, int out_size, void* d_ws, size_t ws_size,
                              hipStream_t stream) {
  const float* self_users = (const float*)d_in[0];
  const float* self_items = (const float*)d_in[1];
  const float* self_mask  = (const float*)d_in[2];
  const float* soc_users  = (const float*)d_in[3];
  const float* soc_items  = (const float*)d_in[4];
  const float* soc_mask   = (const float*)d_in[5];
  const float* ml_user_w  = (const float*)d_in[6];
  const float* ml_user_b  = (const float*)d_in[7];
  const float* ml_w1      = (const float*)d_in[8];
  const float* ml_b1      = (const float*)d_in[9];
  const float* ml_w2      = (const float*)d_in[10];

  char* ws = (char*)d_ws;
  __hip_bfloat16* agg = (__hip_bfloat16*)ws;               // 17,301,504 B
  __hip_bfloat16* wb  = (__hip_bfloat16*)(ws + 17301504);  //  1,048,576 B
  float* selfE        = (float*)(ws + 18350080);           //    524,288 B
  float* social_attn  = (float*)(ws + 18874368);           //    524,288 B
  float* scores       = (float*)(ws + 19398656);           //      2,048 B
  float* partial      = (float*)(ws + 19400704);           //     32,768 B

  hipLaunchKernelGGL(agg_cvt_kernel, dim3(2 * M_ROWS + 128), dim3(256), 0, stream,
                     self_users, self_items, self_mask, soc_users, soc_items,
                     soc_mask, ml_user_w, agg, wb);
  hipLaunchKernelGGL(fused_kernel, dim3(B_), dim3(512), 0, stream,
                     agg, wb, ml_user_b, ml_w1, ml_b1, ml_w2,
                     selfE, social_attn, scores);
  hipLaunchKernelGGL(pool_partial_kernel, dim3(16), dim3(256), 0, stream,
                     selfE, social_attn, scores, partial);
  hipLaunchKernelGGL(pool_final_kernel, dim3(2), dim3(256), 0, stream,
                     partial, (float*)d_out);
}